// Round 5
// baseline (495.703 us; speedup 1.0000x reference)
//
#include <hip/hip_runtime.h>

#define D 64
#define EPS 0.0625f

typedef __attribute__((ext_vector_type(8))) short bf16x8;
typedef __attribute__((ext_vector_type(4))) float f32x4;

// RNE fp32 -> bf16 (bit trick; matches HW cvt for normal values)
static __device__ __forceinline__ short f2bf(float x) {
    unsigned u = __float_as_uint(x);
    unsigned r = u + 0x7fff + ((u >> 16) & 1);
    return (short)(r >> 16);
}
static __device__ __forceinline__ float bf2f(short s) {
    return __uint_as_float(((unsigned)(unsigned short)s) << 16);
}

// Convert centroids fp32 -> (hi, lo) bf16 pair; also zero the flag counter.
__global__ void cvt_kernel(const float* __restrict__ c, short* __restrict__ ch,
                           short* __restrict__ cl, int n, int* __restrict__ counter) {
    int i = blockIdx.x * blockDim.x + threadIdx.x;
    if (i == 0) *counter = 0;
    if (i >= n) return;
    float x = c[i];
    short h = f2bf(x);
    float r = x - bf2f(h);   // exact in fp32
    ch[i] = h;
    cl[i] = f2bf(r);
}

// c2[k] = ||centroid_k||^2 (exact fp32)
__global__ void c2_kernel(const float* __restrict__ centroids,
                          float* __restrict__ c2, int K) {
    int k = blockIdx.x * blockDim.x + threadIdx.x;
    if (k >= K) return;
    const float4* cp = (const float4*)(centroids + (size_t)k * D);
    float s = 0.f;
#pragma unroll
    for (int i = 0; i < D / 4; ++i) {
        float4 v = cp[i];
        s += v.x * v.x; s += v.y * v.y; s += v.z * v.z; s += v.w * v.w;
    }
    c2[k] = s;
}

// Pass 1: split-bf16 MFMA distance scan with top-2 argmin tracking.
// score(n,k) = c2[k] - 2 * dot(a_n, c_k);  dot ~= ah.ch + ah.cl + al.ch
// Wave tile: 32 points (mi=0,1) x all K centroids. No LDS; B streams via L1/L2.
// MFMA 16x16x32 layouts (m89-verified): A[m=lane&15][k=quad*8+j],
// B[k=quad*8+j][n=lane&15] (row-major [n][k] source), C/D col=lane&15,
// row=quad*4+reg.
__global__ __launch_bounds__(256) void pass1_kernel(
    const float* __restrict__ action, const short* __restrict__ ch,
    const short* __restrict__ cl, const float* __restrict__ c2,
    float4* __restrict__ cand, int N, int K) {
    const int tid  = threadIdx.x;
    const int wv   = tid >> 6;
    const int lane = tid & 63;
    const int col  = lane & 15;
    const int quad = lane >> 4;
    const int m0   = blockIdx.x * 128 + wv * 32;

    // A fragments: fp32 -> (hi, lo) bf16 in registers, once.
    bf16x8 ah[2][2], al[2][2];
#pragma unroll
    for (int mi = 0; mi < 2; ++mi) {
        const float* arow = action + (size_t)(m0 + mi * 16 + col) * D;
#pragma unroll
        for (int ks = 0; ks < 2; ++ks) {
            const float* src = arow + ks * 32 + quad * 8;
            bf16x8 h, l;
#pragma unroll
            for (int j = 0; j < 8; ++j) {
                float x = src[j];
                short hs = f2bf(x);
                h[j] = hs;
                l[j] = f2bf(x - bf2f(hs));
            }
            ah[mi][ks] = h;
            al[mi][ks] = l;
        }
    }

    // per-lane top-2 state for 8 (mi,reg) points
    float b1[8], b2[8];
    int   bk[8];
#pragma unroll
    for (int e = 0; e < 8; ++e) {
        b1[e] = __builtin_inff(); b2[e] = __builtin_inff(); bk[e] = 0;
    }

    for (int n0 = 0; n0 < K; n0 += 16) {
        const int k = n0 + col;
        const size_t kb = (size_t)k * D + quad * 8;
        bf16x8 bh0 = *(const bf16x8*)(ch + kb);
        bf16x8 bh1 = *(const bf16x8*)(ch + kb + 32);
        bf16x8 bl0 = *(const bf16x8*)(cl + kb);
        bf16x8 bl1 = *(const bf16x8*)(cl + kb + 32);
        float cc = c2[k];
#pragma unroll
        for (int mi = 0; mi < 2; ++mi) {
            f32x4 acc = {0.f, 0.f, 0.f, 0.f};
            acc = __builtin_amdgcn_mfma_f32_16x16x32_bf16(al[mi][0], bh0, acc, 0, 0, 0);
            acc = __builtin_amdgcn_mfma_f32_16x16x32_bf16(ah[mi][0], bl0, acc, 0, 0, 0);
            acc = __builtin_amdgcn_mfma_f32_16x16x32_bf16(ah[mi][0], bh0, acc, 0, 0, 0);
            acc = __builtin_amdgcn_mfma_f32_16x16x32_bf16(al[mi][1], bh1, acc, 0, 0, 0);
            acc = __builtin_amdgcn_mfma_f32_16x16x32_bf16(ah[mi][1], bl1, acc, 0, 0, 0);
            acc = __builtin_amdgcn_mfma_f32_16x16x32_bf16(ah[mi][1], bh1, acc, 0, 0, 0);
#pragma unroll
            for (int r = 0; r < 4; ++r) {
                const int e = mi * 4 + r;
                float s = fmaf(-2.f, acc[r], cc);
                bool better = s < b1[e];
                b2[e] = better ? b1[e] : fminf(b2[e], s);
                b1[e] = better ? s : b1[e];
                bk[e] = better ? k : bk[e];
            }
        }
    }

    // cross-lane top-2 merge over the 16 centroid columns (lanes sharing quad)
#pragma unroll
    for (int off = 1; off < 16; off <<= 1) {
#pragma unroll
        for (int e = 0; e < 8; ++e) {
            float o1 = __shfl_xor(b1[e], off, 64);
            float o2 = __shfl_xor(b2[e], off, 64);
            int   ok = __shfl_xor(bk[e], off, 64);
            bool take = (o1 < b1[e]) || (o1 == b1[e] && ok < bk[e]);
            float nb2 = take ? fminf(b1[e], o2) : fminf(b2[e], o1);
            b1[e] = take ? o1 : b1[e];
            bk[e] = take ? ok : bk[e];
            b2[e] = nb2;
        }
    }

    if (col == 0) {
#pragma unroll
        for (int e = 0; e < 8; ++e) {
            const int mi = e >> 2, r = e & 3;
            const int p = m0 + mi * 16 + quad * 4 + r;
            cand[p] = make_float4(b1[e], b2[e], (float)bk[e], 0.f);
        }
    }
}

// F1: write bin for all points; append gap<EPS points to the exact-rescan list.
__global__ void flag_kernel(const float4* __restrict__ cand,
                            float* __restrict__ out_bin,
                            int* __restrict__ counter, int* __restrict__ flags,
                            int N) {
    int n = blockIdx.x * blockDim.x + threadIdx.x;
    if (n >= N) return;
    float4 v = cand[n];
    out_bin[n] = v.z;
    if (v.y - v.x < EPS) {
        int idx = atomicAdd(counter, 1);
        flags[idx] = n;
    }
}

// Residuals for all points in exact fp32 (flagged points overwritten by F2).
__global__ void res_kernel(const float* __restrict__ action,
                           const float* __restrict__ centroids,
                           const float4* __restrict__ cand,
                           float* __restrict__ out_res, int N) {
    int idx = blockIdx.x * blockDim.x + threadIdx.x;  // over N*16 float4s
    if (idx >= N * 16) return;
    int n = idx >> 4, j = idx & 15;
    int bk = (int)cand[n].z;
    float4 av = ((const float4*)action)[idx];
    float4 cv = ((const float4*)centroids)[bk * 16 + j];
    ((float4*)out_res)[idx] =
        make_float4(av.x - cv.x, av.y - cv.y, av.z - cv.z, av.w - cv.w);
}

// F2: exact fp32 rescan of all K centroids for flagged points.
// One block per flagged point (grid-stride). numpy first-min tie-break.
__global__ __launch_bounds__(256) void exact_kernel(
    const float* __restrict__ action, const float* __restrict__ centroids,
    const float* __restrict__ c2, const int* __restrict__ counter,
    const int* __restrict__ flags, float* __restrict__ out_bin,
    float* __restrict__ out_res, int K) {
    __shared__ float sa[D];
    __shared__ float sv[256];
    __shared__ int   sk[256];
    __shared__ int   s_bk;
    const int count = *counter;
    for (int i = blockIdx.x; i < count; i += gridDim.x) {
        const int n = flags[i];
        __syncthreads();
        if (threadIdx.x < D) sa[threadIdx.x] = action[(size_t)n * D + threadIdx.x];
        __syncthreads();
        float best = __builtin_inff();
        int bbk = 0x7fffffff;
        for (int k = threadIdx.x; k < K; k += 256) {
            const float* crow = centroids + (size_t)k * D;
            float dot = 0.f;
#pragma unroll
            for (int d = 0; d < D; ++d) dot = fmaf(sa[d], crow[d], dot);
            float s = fmaf(-2.f, dot, c2[k]);
            if (s < best) { best = s; bbk = k; }  // ascending k: first-min
        }
        sv[threadIdx.x] = best;
        sk[threadIdx.x] = bbk;
        __syncthreads();
        if (threadIdx.x == 0) {
            float bb = sv[0];
            int bki = sk[0];
            for (int t = 1; t < 256; ++t) {
                if (sv[t] < bb || (sv[t] == bb && sk[t] < bki)) {
                    bb = sv[t]; bki = sk[t];
                }
            }
            out_bin[n] = (float)bki;
            s_bk = bki;
        }
        __syncthreads();
        if (threadIdx.x < D) {
            float cvd = centroids[(size_t)s_bk * D + threadIdx.x];
            out_res[(size_t)n * D + threadIdx.x] = sa[threadIdx.x] - cvd;
        }
    }
}

extern "C" void kernel_launch(void* const* d_in, const int* in_sizes, int n_in,
                              void* d_out, int out_size, void* d_ws, size_t ws_size,
                              hipStream_t stream) {
    const float* action    = (const float*)d_in[0];  // [N, 64]
    const float* centroids = (const float*)d_in[1];  // [K, 64]
    const int N = in_sizes[0] / D;  // 65536
    const int K = in_sizes[1] / D;  // 2048

    float* out_bin = (float*)d_out;      // N floats: argmin index
    float* out_res = (float*)d_out + N;  // N*D residuals

    // ws layout (1.76 MB total)
    char* w = (char*)d_ws;
    float*  c2      = (float*)w;                       // K*4      = 8 KB
    int*    counter = (int*)(w + 8192);                // 4 B (padded)
    int*    flags   = (int*)(w + 8448);                // N*4      = 256 KB
    short*  ch      = (short*)(w + 8448 + 262144);     // K*D*2    = 256 KB
    short*  cl      = ch + (size_t)K * D;              //            256 KB
    float4* cand    = (float4*)((char*)(cl + (size_t)K * D));  // N*16 = 1 MB

    const int KD = K * D;
    cvt_kernel<<<(KD + 255) / 256, 256, 0, stream>>>(centroids, ch, cl, KD, counter);
    c2_kernel<<<(K + 255) / 256, 256, 0, stream>>>(centroids, c2, K);
    pass1_kernel<<<N / 128, 256, 0, stream>>>(action, ch, cl, c2, cand, N, K);
    flag_kernel<<<(N + 255) / 256, 256, 0, stream>>>(cand, out_bin, counter, flags, N);
    res_kernel<<<(N * 16 + 255) / 256, 256, 0, stream>>>(action, centroids, cand,
                                                         out_res, N);
    exact_kernel<<<512, 256, 0, stream>>>(action, centroids, c2, counter, flags,
                                          out_bin, out_res, K);
}

// Round 6
// 235.998 us; speedup vs baseline: 2.1005x; 2.1005x over previous
//
#include <hip/hip_runtime.h>

#define D 64
#define EPS 0.006f
#define KSPLIT 2

typedef __attribute__((ext_vector_type(8))) short bf16x8;
typedef __attribute__((ext_vector_type(4))) float f32x4;

// RNE fp32 -> bf16 (bit trick; matches HW cvt for normal values)
static __device__ __forceinline__ short f2bf(float x) {
    unsigned u = __float_as_uint(x);
    unsigned r = u + 0x7fff + ((u >> 16) & 1);
    return (short)(r >> 16);
}
static __device__ __forceinline__ float bf2f(short s) {
    return __uint_as_float(((unsigned)(unsigned short)s) << 16);
}

// Convert centroids fp32 -> (hi, lo) bf16 pair; also zero the flag counter.
__global__ void cvt_kernel(const float* __restrict__ c, short* __restrict__ ch,
                           short* __restrict__ cl, int n, int* __restrict__ counter) {
    int i = blockIdx.x * blockDim.x + threadIdx.x;
    if (i == 0) *counter = 0;
    if (i >= n) return;
    float x = c[i];
    short h = f2bf(x);
    ch[i] = h;
    cl[i] = f2bf(x - bf2f(h));
}

// c2[k] = ||centroid_k||^2 (exact fp32)
__global__ void c2_kernel(const float* __restrict__ centroids,
                          float* __restrict__ c2, int K) {
    int k = blockIdx.x * blockDim.x + threadIdx.x;
    if (k >= K) return;
    const float4* cp = (const float4*)(centroids + (size_t)k * D);
    float s = 0.f;
#pragma unroll
    for (int i = 0; i < D / 4; ++i) {
        float4 v = cp[i];
        s += v.x * v.x; s += v.y * v.y; s += v.z * v.z; s += v.w * v.w;
    }
    c2[k] = s;
}

// Pass 1: split-bf16 MFMA distance scan, top-2 tracking, K split over
// blockIdx.y (KSPLIT) for occupancy. Register double-buffer on B loads.
// score(n,k) = c2[k] - 2*dot(a,c); dot ~= ah.ch + ah.cl + al.ch
// MFMA 16x16x32 layouts (m89-verified): A[m=lane&15][k=quad*8+j],
// B[k=quad*8+j][n=lane&15], C/D col=lane&15, row=quad*4+reg.
__global__ __launch_bounds__(256) void pass1_kernel(
    const float* __restrict__ action, const short* __restrict__ ch,
    const short* __restrict__ cl, const float* __restrict__ c2,
    float4* __restrict__ cand, int N, int K) {
    const int tid  = threadIdx.x;
    const int wv   = tid >> 6;
    const int lane = tid & 63;
    const int col  = lane & 15;
    const int quad = lane >> 4;
    const int m0   = blockIdx.x * 128 + wv * 32;
    const int KC   = K / KSPLIT;
    const int k0   = blockIdx.y * KC;
    const int k1   = k0 + KC;

    // A fragments: fp32 -> (hi, lo) bf16 in registers, once.
    bf16x8 ah[2][2], al[2][2];
#pragma unroll
    for (int mi = 0; mi < 2; ++mi) {
        const float* arow = action + (size_t)(m0 + mi * 16 + col) * D;
#pragma unroll
        for (int ks = 0; ks < 2; ++ks) {
            const float* src = arow + ks * 32 + quad * 8;
            bf16x8 h, l;
#pragma unroll
            for (int j = 0; j < 8; ++j) {
                float x = src[j];
                short hs = f2bf(x);
                h[j] = hs;
                l[j] = f2bf(x - bf2f(hs));
            }
            ah[mi][ks] = h;
            al[mi][ks] = l;
        }
    }

    float b1[8], b2[8];
    int   bk[8];
#pragma unroll
    for (int e = 0; e < 8; ++e) {
        b1[e] = __builtin_inff(); b2[e] = __builtin_inff(); bk[e] = k0;
    }

    // prologue prefetch (iter 0)
    bf16x8 pbh0, pbh1, pbl0, pbl1;
    float  pcc;
    {
        const size_t kb = (size_t)(k0 + col) * D + quad * 8;
        pbh0 = *(const bf16x8*)(ch + kb);
        pbh1 = *(const bf16x8*)(ch + kb + 32);
        pbl0 = *(const bf16x8*)(cl + kb);
        pbl1 = *(const bf16x8*)(cl + kb + 32);
        pcc  = c2[k0 + col];
    }

#pragma unroll 2
    for (int n0 = k0; n0 < k1; n0 += 16) {
        bf16x8 bh0 = pbh0, bh1 = pbh1, bl0 = pbl0, bl1 = pbl1;
        const float cc = pcc;
        const int   k  = n0 + col;

        // prefetch next iteration (hides L2 latency under MFMA+fold)
        const int np = n0 + 16;
        if (np < k1) {
            const size_t kb = (size_t)(np + col) * D + quad * 8;
            pbh0 = *(const bf16x8*)(ch + kb);
            pbh1 = *(const bf16x8*)(ch + kb + 32);
            pbl0 = *(const bf16x8*)(cl + kb);
            pbl1 = *(const bf16x8*)(cl + kb + 32);
            pcc  = c2[np + col];
        }

#pragma unroll
        for (int mi = 0; mi < 2; ++mi) {
            f32x4 acc = {0.f, 0.f, 0.f, 0.f};
            acc = __builtin_amdgcn_mfma_f32_16x16x32_bf16(al[mi][0], bh0, acc, 0, 0, 0);
            acc = __builtin_amdgcn_mfma_f32_16x16x32_bf16(ah[mi][0], bl0, acc, 0, 0, 0);
            acc = __builtin_amdgcn_mfma_f32_16x16x32_bf16(ah[mi][0], bh0, acc, 0, 0, 0);
            acc = __builtin_amdgcn_mfma_f32_16x16x32_bf16(al[mi][1], bh1, acc, 0, 0, 0);
            acc = __builtin_amdgcn_mfma_f32_16x16x32_bf16(ah[mi][1], bl1, acc, 0, 0, 0);
            acc = __builtin_amdgcn_mfma_f32_16x16x32_bf16(ah[mi][1], bh1, acc, 0, 0, 0);
#pragma unroll
            for (int r = 0; r < 4; ++r) {
                const int e = mi * 4 + r;
                const float s = fmaf(-2.f, acc[r], cc);
                const float mid = fmaxf(s, b1[e]);     // loser of (s, b1)
                b2[e] = fminf(b2[e], mid);
                const bool better = s < b1[e];          // strict <: first-min
                b1[e] = fminf(b1[e], s);
                bk[e] = better ? k : bk[e];
            }
        }
    }

    // cross-lane top-2 merge over the 16 centroid columns
#pragma unroll
    for (int off = 1; off < 16; off <<= 1) {
#pragma unroll
        for (int e = 0; e < 8; ++e) {
            float o1 = __shfl_xor(b1[e], off, 64);
            float o2 = __shfl_xor(b2[e], off, 64);
            int   ok = __shfl_xor(bk[e], off, 64);
            bool take = (o1 < b1[e]) || (o1 == b1[e] && ok < bk[e]);
            float nb2 = take ? fminf(b1[e], o2) : fminf(b2[e], o1);
            b1[e] = take ? o1 : b1[e];
            bk[e] = take ? ok : bk[e];
            b2[e] = nb2;
        }
    }

    if (col == 0) {
#pragma unroll
        for (int e = 0; e < 8; ++e) {
            const int mi = e >> 2, r = e & 3;
            const int p = m0 + mi * 16 + quad * 4 + r;
            cand[(size_t)blockIdx.y * N + p] =
                make_float4(b1[e], b2[e], (float)bk[e], 0.f);
        }
    }
}

// Merge split candidates (exact top-2: splits are disjoint, split0 owns the
// lower indices so equality -> split0 = numpy first-min), write bin, flag
// ambiguous points for exact rescan.
__global__ void flag_kernel(const float4* __restrict__ cand,
                            float* __restrict__ out_bin,
                            int* __restrict__ counter, int* __restrict__ flags,
                            int N) {
    int n = blockIdx.x * blockDim.x + threadIdx.x;
    if (n >= N) return;
    float4 v0 = cand[n];
    float4 v1 = cand[(size_t)N + n];
    float b1, b2; int bk;
    if (v1.x < v0.x) { b1 = v1.x; bk = (int)v1.z; b2 = fminf(v0.x, v1.y); }
    else             { b1 = v0.x; bk = (int)v0.z; b2 = fminf(v1.x, v0.y); }
    out_bin[n] = (float)bk;
    if (b2 - b1 < EPS) {
        int idx = atomicAdd(counter, 1);
        flags[idx] = n;
    }
}

// Residuals for all points in exact fp32 (flagged points overwritten later).
__global__ void res_kernel(const float* __restrict__ action,
                           const float* __restrict__ centroids,
                           const float* __restrict__ out_bin,
                           float* __restrict__ out_res, int N) {
    int idx = blockIdx.x * blockDim.x + threadIdx.x;  // over N*16 float4s
    if (idx >= N * 16) return;
    int n = idx >> 4, j = idx & 15;
    int bk = (int)out_bin[n];
    float4 av = ((const float4*)action)[idx];
    float4 cv = ((const float4*)centroids)[bk * 16 + j];
    ((float4*)out_res)[idx] =
        make_float4(av.x - cv.x, av.y - cv.y, av.z - cv.z, av.w - cv.w);
}

// Exact fp32 rescan of all K centroids for flagged points.
// One block per flagged point (grid-stride). numpy first-min tie-break.
__global__ __launch_bounds__(256) void exact_kernel(
    const float* __restrict__ action, const float* __restrict__ centroids,
    const float* __restrict__ c2, const int* __restrict__ counter,
    const int* __restrict__ flags, float* __restrict__ out_bin,
    float* __restrict__ out_res, int K) {
    __shared__ float4 sa[D / 4];
    __shared__ float  swv[4];
    __shared__ int    swk[4];
    __shared__ int    s_bk;
    const int count = *counter;
    const int tid = threadIdx.x, lane = tid & 63, wid = tid >> 6;
    for (int i = blockIdx.x; i < count; i += gridDim.x) {
        const int n = flags[i];
        __syncthreads();
        if (tid < D / 4) sa[tid] = ((const float4*)(action + (size_t)n * D))[tid];
        __syncthreads();
        float best = __builtin_inff();
        int bbk = 0x7fffffff;
        for (int k = tid; k < K; k += 256) {
            const float4* cr = (const float4*)(centroids + (size_t)k * D);
            float dot = 0.f;
#pragma unroll
            for (int d = 0; d < D / 4; ++d) {
                float4 a = sa[d], c = cr[d];
                dot = fmaf(a.x, c.x, dot); dot = fmaf(a.y, c.y, dot);
                dot = fmaf(a.z, c.z, dot); dot = fmaf(a.w, c.w, dot);
            }
            float s = fmaf(-2.f, dot, c2[k]);
            if (s < best) { best = s; bbk = k; }  // ascending k: first-min
        }
        // wave reduce with (score, index) lexicographic tie-break
#pragma unroll
        for (int off = 32; off > 0; off >>= 1) {
            float ov = __shfl_down(best, off, 64);
            int   ok = __shfl_down(bbk, off, 64);
            if (ov < best || (ov == best && ok < bbk)) { best = ov; bbk = ok; }
        }
        if (lane == 0) { swv[wid] = best; swk[wid] = bbk; }
        __syncthreads();
        if (tid == 0) {
            float bb = swv[0]; int bki = swk[0];
#pragma unroll
            for (int t = 1; t < 4; ++t)
                if (swv[t] < bb || (swv[t] == bb && swk[t] < bki)) {
                    bb = swv[t]; bki = swk[t];
                }
            out_bin[n] = (float)bki;
            s_bk = bki;
        }
        __syncthreads();
        if (tid < D / 4) {
            float4 a = sa[tid];
            float4 c = ((const float4*)(centroids + (size_t)s_bk * D))[tid];
            ((float4*)(out_res + (size_t)n * D))[tid] =
                make_float4(a.x - c.x, a.y - c.y, a.z - c.z, a.w - c.w);
        }
    }
}

extern "C" void kernel_launch(void* const* d_in, const int* in_sizes, int n_in,
                              void* d_out, int out_size, void* d_ws, size_t ws_size,
                              hipStream_t stream) {
    const float* action    = (const float*)d_in[0];  // [N, 64]
    const float* centroids = (const float*)d_in[1];  // [K, 64]
    const int N = in_sizes[0] / D;  // 65536
    const int K = in_sizes[1] / D;  // 2048

    float* out_bin = (float*)d_out;      // N floats: argmin index
    float* out_res = (float*)d_out + N;  // N*D residuals

    // ws layout (~2.8 MB)
    char* w = (char*)d_ws;
    float*  c2      = (float*)w;                       // 8 KB
    int*    counter = (int*)(w + 8192);                // 4 B (padded to 256)
    int*    flags   = (int*)(w + 8448);                // N*4 = 256 KB
    short*  ch      = (short*)(w + 8448 + 262144);     // K*D*2 = 256 KB
    short*  cl      = ch + (size_t)K * D;              // 256 KB
    float4* cand    = (float4*)(cl + (size_t)K * D);   // KSPLIT*N*16 = 2 MB

    const int KD = K * D;
    cvt_kernel<<<(KD + 255) / 256, 256, 0, stream>>>(centroids, ch, cl, KD, counter);
    c2_kernel<<<(K + 255) / 256, 256, 0, stream>>>(centroids, c2, K);
    dim3 g1(N / 128, KSPLIT);
    pass1_kernel<<<g1, 256, 0, stream>>>(action, ch, cl, c2, cand, N, K);
    flag_kernel<<<(N + 255) / 256, 256, 0, stream>>>(cand, out_bin, counter, flags, N);
    res_kernel<<<(N * 16 + 255) / 256, 256, 0, stream>>>(action, centroids, out_bin,
                                                         out_res, N);
    exact_kernel<<<1024, 256, 0, stream>>>(action, centroids, c2, counter, flags,
                                           out_bin, out_res, K);
}